// Round 5
// baseline (510.569 us; speedup 1.0000x reference)
//
#include <hip/hip_runtime.h>

// HyperbolicAttention: N=100000 nodes, C=128, H=8 heads, D=16, E=640000 edges.
// Round 5: swapped-operand MFMA GEMM (vectorized stores, LDS frag-major W),
//          head-major bf16 Q/K/V for per-head L2 residency, stats fused into
//          edge_scores, per-head gather.

#define TPB 256

typedef __attribute__((ext_vector_type(8))) short short8;
typedef __attribute__((ext_vector_type(4))) short short4v;
typedef __attribute__((ext_vector_type(4))) float f32x4;

// fp32 -> bf16 round-to-nearest-even
__device__ __forceinline__ short f2bf(float f) {
    unsigned u = __float_as_uint(f);
    u += 0x7fffu + ((u >> 16) & 1u);
    return (short)(u >> 16);
}
// bf16 -> fp32
__device__ __forceinline__ float bf2f(short s) {
    return __uint_as_float(((unsigned)(unsigned short)s) << 16);
}

// ---------------------------------------------------------------------------
// Convert the four 128x128 fp32 weight matrices to bf16 (row-major, packed).
// ---------------------------------------------------------------------------
__global__ void wconv_kernel(const float* __restrict__ W0, const float* __restrict__ W1,
                             const float* __restrict__ W2, const float* __restrict__ W3,
                             short* __restrict__ out)
{
    int i = blockIdx.x * TPB + threadIdx.x;   // 0..65535
    if (i >= 65536) return;
    const float* W = (i < 16384) ? W0 : (i < 32768) ? W1 : (i < 49152) ? W2 : W3;
    out[i] = f2bf(W[i & 16383]);
}

// ---------------------------------------------------------------------------
// Y = X @ W^T + b. X:[nrows,128] fp32, W bf16 [128][128].
// Swapped-operand MFMA: acc = mfma(Wfrag, Xfrag, acc) computes D[i][col] =
// Y[x-row=col][w-row=n*16+i]; lane holds row=l15 (x-row), 4 consecutive output
// cols n*16+lh*4+j -> vectorized 8B/16B stores.
// Block = 4 waves x 32 rows = 128 rows. W staged in LDS frag-major
// (chunk = (n*4+kc)*64+lane -> conflict-free ds_read_b128).
// HEADMAJOR: write bf16 to Y[(n*Ntot+row)*16 + lh*4] (head n).
// else: write fp32 row-major Y[row*128 + n*16 + lh*4].
// ---------------------------------------------------------------------------
template<bool HEADMAJOR>
__global__ __launch_bounds__(256) void gemm_w_kernel(
    const float* __restrict__ X, int nrows, int Ntot,
    const short* __restrict__ Wb, const float* __restrict__ bias,
    void* __restrict__ Yv)
{
    __shared__ short lw[16384];   // 32 KiB W, frag-major
    const int tid = threadIdx.x;

    #pragma unroll
    for (int r = 0; r < 8; ++r) {
        int c = r * 256 + tid;              // chunk id 0..2047
        int fragid = c >> 6, ln = c & 63;
        int n = fragid >> 2, kc = fragid & 3;
        int row = n * 16 + (ln & 15);
        int col = kc * 32 + (ln >> 4) * 8;
        *(short8*)&lw[c * 8] = *(const short8*)&Wb[row * 128 + col];
    }
    __syncthreads();

    const int wid = tid >> 6;
    const int lane = tid & 63;
    const int l15 = lane & 15;
    const int lh  = lane >> 4;
    const int rowbase = blockIdx.x * 128 + wid * 32;

    f32x4 acc[8][2];
    #pragma unroll
    for (int n = 0; n < 8; ++n) { acc[n][0] = (f32x4)0.f; acc[n][1] = (f32x4)0.f; }

    const int r0 = rowbase + l15, r1 = rowbase + 16 + l15;
    const bool v0 = r0 < nrows, v1 = r1 < nrows;
    const float4* X0 = reinterpret_cast<const float4*>(X + (size_t)r0 * 128);
    const float4* X1 = reinterpret_cast<const float4*>(X + (size_t)r1 * 128);

    #pragma unroll
    for (int kc = 0; kc < 4; ++kc) {
        short8 xf[2];
        xf[0] = (short8)(short)0; xf[1] = (short8)(short)0;
        if (v0) {
            float4 a = X0[kc*8 + lh*2], b = X0[kc*8 + lh*2 + 1];
            xf[0][0]=f2bf(a.x); xf[0][1]=f2bf(a.y); xf[0][2]=f2bf(a.z); xf[0][3]=f2bf(a.w);
            xf[0][4]=f2bf(b.x); xf[0][5]=f2bf(b.y); xf[0][6]=f2bf(b.z); xf[0][7]=f2bf(b.w);
        }
        if (v1) {
            float4 a = X1[kc*8 + lh*2], b = X1[kc*8 + lh*2 + 1];
            xf[1][0]=f2bf(a.x); xf[1][1]=f2bf(a.y); xf[1][2]=f2bf(a.z); xf[1][3]=f2bf(a.w);
            xf[1][4]=f2bf(b.x); xf[1][5]=f2bf(b.y); xf[1][6]=f2bf(b.z); xf[1][7]=f2bf(b.w);
        }
        short8 wf[8];
        #pragma unroll
        for (int n = 0; n < 8; ++n)
            wf[n] = *(const short8*)&lw[((n*4 + kc)*64 + lane) * 8];
        #pragma unroll
        for (int n = 0; n < 8; ++n) {
            acc[n][0] = __builtin_amdgcn_mfma_f32_16x16x32_bf16(wf[n], xf[0], acc[n][0], 0, 0, 0);
            acc[n][1] = __builtin_amdgcn_mfma_f32_16x16x32_bf16(wf[n], xf[1], acc[n][1], 0, 0, 0);
        }
    }

    #pragma unroll
    for (int g = 0; g < 2; ++g) {
        int row = rowbase + g*16 + l15;
        if (row >= nrows) continue;
        #pragma unroll
        for (int n = 0; n < 8; ++n) {
            float4 b4 = *(const float4*)&bias[n*16 + lh*4];
            float y0 = acc[n][g][0] + b4.x;
            float y1 = acc[n][g][1] + b4.y;
            float y2 = acc[n][g][2] + b4.z;
            float y3 = acc[n][g][3] + b4.w;
            if (HEADMAJOR) {
                short4v s; s[0]=f2bf(y0); s[1]=f2bf(y1); s[2]=f2bf(y2); s[3]=f2bf(y3);
                *(short4v*)&((short*)Yv)[((size_t)n * Ntot + row) * 16 + lh*4] = s;
            } else {
                *(float4*)&((float*)Yv)[(size_t)row * 128 + n*16 + lh*4] =
                    make_float4(y0, y1, y2, y3);
            }
        }
    }
}

// ---------------------------------------------------------------------------
// edge_index may arrive as int64 (reference) or int32. Detect on device.
// ---------------------------------------------------------------------------
__global__ void detect_i64_kernel(const int* __restrict__ raw, int* __restrict__ flag)
{
    if (blockIdx.x == 0 && threadIdx.x == 0) {
        int odd_nonzero = 0;
        for (int i = 0; i < 128; ++i)
            if (raw[2 * i + 1] != 0) odd_nonzero = 1;
        *flag = odd_nonzero ? 0 : 1;  // 1 => int64 layout
    }
}

__global__ void conv_idx_kernel(const void* __restrict__ raw, int n,
                                const int* __restrict__ flag, int* __restrict__ out)
{
    int i = blockIdx.x * TPB + threadIdx.x;
    if (i >= n) return;
    if (*flag) out[i] = (int)((const long long*)raw)[i];
    else       out[i] = ((const int*)raw)[i];
}

// ---------------------------------------------------------------------------
// Per-edge scores for one head (blockIdx.y = h), head-major bf16 Q/K.
// S[h*E+e] = q . k / 4. Fused per-block online softmax (m,z) partials.
// ---------------------------------------------------------------------------
__global__ __launch_bounds__(256) void edge_score_stats_kernel(
    const short* __restrict__ Qb, const short* __restrict__ Kb,
    const int* __restrict__ ei, int E, int Ntot,
    float* __restrict__ S, float* __restrict__ mpart, float* __restrict__ zpart)
{
    int t = threadIdx.x;
    int e = blockIdx.x * TPB + t;
    int h = blockIdx.y;
    float m = -3.0e38f, z = 0.f;
    if (e < E) {
        int r = ei[e], c = ei[E + e];
        const short8* q8 = (const short8*)(Qb + ((size_t)h * Ntot + r) * 16);
        const short8* k8 = (const short8*)(Kb + ((size_t)h * Ntot + c) * 16);
        short8 q0 = q8[0], q1 = q8[1], k0 = k8[0], k1 = k8[1];
        float dot = 0.f;
        #pragma unroll
        for (int i = 0; i < 8; ++i) {
            dot += bf2f(q0[i]) * bf2f(k0[i]);
            dot += bf2f(q1[i]) * bf2f(k1[i]);
        }
        float s = dot * 0.25f;  // 1/sqrt(16)
        S[(size_t)h * E + e] = s;
        m = s; z = 1.f;
    }
    __shared__ float sm[TPB], sz[TPB];
    sm[t] = m; sz[t] = z;
    __syncthreads();
    for (int off = 128; off >= 1; off >>= 1) {
        if (t < off) {
            float m2 = sm[t + off], z2 = sz[t + off];
            float M = fmaxf(sm[t], m2);
            sz[t] = sz[t] * __expf(sm[t] - M) + z2 * __expf(m2 - M);
            sm[t] = M;
        }
        __syncthreads();
    }
    if (t == 0) {
        mpart[h * gridDim.x + blockIdx.x] = sm[0];
        zpart[h * gridDim.x + blockIdx.x] = sz[0];
    }
}

// One block per head: combine nb partials -> MZ[h] (max), MZ[8+h] (Z).
__global__ void stats_reduce_kernel(const float* __restrict__ mpart,
                                    const float* __restrict__ zpart,
                                    int nb, float* __restrict__ MZ)
{
    int h = blockIdx.x, t = threadIdx.x;
    float m = -3.0e38f, z = 0.f;
    for (int i = t; i < nb; i += TPB) {
        float m2 = mpart[h * nb + i], z2 = zpart[h * nb + i];
        float M = fmaxf(m, m2);
        z = z * __expf(m - M) + z2 * __expf(m2 - M);
        m = M;
    }
    __shared__ float sm[TPB], sz[TPB];
    sm[t] = m; sz[t] = z;
    __syncthreads();
    for (int off = 128; off >= 1; off >>= 1) {
        if (t < off) {
            float m2 = sm[t + off], z2 = sz[t + off];
            float M = fmaxf(sm[t], m2);
            sz[t] = sz[t] * __expf(sm[t] - M) + z2 * __expf(m2 - M);
            sm[t] = M;
        }
        __syncthreads();
    }
    if (t == 0) { MZ[h] = sm[0]; MZ[8 + h] = sz[0]; }
}

// ---------------------------------------------------------------------------
// CSR build: histogram by destination row, exclusive scan, binned fill.
// ---------------------------------------------------------------------------
__global__ void hist_kernel(const int* __restrict__ rows, int E, int* __restrict__ deg)
{
    int e = blockIdx.x * TPB + threadIdx.x;
    if (e < E) atomicAdd(&deg[rows[e]], 1);
}

__global__ void scan1_kernel(const int* __restrict__ deg, int n,
                             int* __restrict__ rowstart, int* __restrict__ bsum)
{
    __shared__ int sm[TPB];
    int t = threadIdx.x;
    int gid = blockIdx.x * TPB + t;
    int v = (gid < n) ? deg[gid] : 0;
    sm[t] = v;
    __syncthreads();
    for (int off = 1; off < TPB; off <<= 1) {
        int x = (t >= off) ? sm[t - off] : 0;
        __syncthreads();
        sm[t] += x;
        __syncthreads();
    }
    if (gid < n) rowstart[gid] = sm[t] - v;
    if (t == TPB - 1) bsum[blockIdx.x] = sm[t];
}

__global__ void scan2_kernel(int* __restrict__ bsum, int nb)
{
    __shared__ int sm[512];
    int t = threadIdx.x;
    int v = (t < nb) ? bsum[t] : 0;
    sm[t] = v;
    __syncthreads();
    for (int off = 1; off < 512; off <<= 1) {
        int x = (t >= off) ? sm[t - off] : 0;
        __syncthreads();
        sm[t] += x;
        __syncthreads();
    }
    if (t < nb) bsum[t] = sm[t] - v;
}

__global__ void scan3_kernel(int* __restrict__ rowstart, int n, int E,
                             const int* __restrict__ bsum)
{
    int gid = blockIdx.x * TPB + threadIdx.x;
    if (gid < n) rowstart[gid] += bsum[blockIdx.x];
    if (gid == 0) rowstart[n] = E;
}

__global__ void fill_kernel(const int* __restrict__ rows, int E,
                            int* __restrict__ cursor, int* __restrict__ elist)
{
    int e = blockIdx.x * TPB + threadIdx.x;
    if (e >= E) return;
    int pos = atomicAdd(&cursor[rows[e]], 1);
    elist[pos] = e;
}

// ---------------------------------------------------------------------------
// Per-head gather segment-sum (blockIdx.y = h), head-major bf16 V (L2-resident
// 3.2 MB slice). out[node, h*16 .. h*16+15] = sum_e w * V_h[col[e]].
// ---------------------------------------------------------------------------
__global__ __launch_bounds__(256) void gather_kernel(
    const float* __restrict__ S, const short* __restrict__ Vb,
    const int* __restrict__ cols,
    const int* __restrict__ rowstart, const int* __restrict__ elist,
    const float* __restrict__ MZ, int N, int E,
    float* __restrict__ out)
{
    int node = blockIdx.x * TPB + threadIdx.x;
    int h = blockIdx.y;
    if (node >= N) return;
    float M = MZ[h];
    float invZ = 1.0f / MZ[8 + h];
    int p0 = rowstart[node], p1 = rowstart[node + 1];

    float a[16];
    #pragma unroll
    for (int i = 0; i < 16; ++i) a[i] = 0.f;

    for (int p = p0; p < p1; ++p) {
        int e = elist[p];
        int c = cols[e];
        float w = __expf(S[(size_t)h * E + e] - M) * invZ;
        const short8* v8 = (const short8*)(Vb + ((size_t)h * N + c) * 16);
        short8 v0 = v8[0], v1 = v8[1];
        #pragma unroll
        for (int i = 0; i < 8; ++i) {
            a[i]     += w * bf2f(v0[i]);
            a[8 + i] += w * bf2f(v1[i]);
        }
    }
    float4* o4 = reinterpret_cast<float4*>(out + (size_t)node * 128 + h * 16);
    o4[0] = make_float4(a[0],  a[1],  a[2],  a[3]);
    o4[1] = make_float4(a[4],  a[5],  a[6],  a[7]);
    o4[2] = make_float4(a[8],  a[9],  a[10], a[11]);
    o4[3] = make_float4(a[12], a[13], a[14], a[15]);
}

// ---------------------------------------------------------------------------
extern "C" void kernel_launch(void* const* d_in, const int* in_sizes, int n_in,
                              void* d_out, int out_size, void* d_ws, size_t ws_size,
                              hipStream_t stream)
{
    const float* feat = (const float*)d_in[0];
    const void*  eraw = d_in[1];
    const float* Wq = (const float*)d_in[2];
    const float* bq = (const float*)d_in[3];
    const float* Wk = (const float*)d_in[4];
    const float* bk = (const float*)d_in[5];
    const float* Wv = (const float*)d_in[6];
    const float* bv = (const float*)d_in[7];
    const float* Wo = (const float*)d_in[8];
    const float* bo = (const float*)d_in[9];

    const int N = in_sizes[0] / 128;
    const int E = in_sizes[1] / 2;
    const size_t NC = (size_t)N * 128;
    const int EB = (E + TPB - 1) / TPB;    // edge blocks per head

    // Workspace layout
    short* Qb  = (short*)d_ws;             // [8][N][16] bf16
    short* Kb  = Qb + NC;                  // [8][N][16] bf16
    short* Vb  = Kb + NC;                  // [8][N][16] bf16
    float* ACC = (float*)(Vb + NC);        // [N][128] fp32
    float* S   = ACC + NC;                 // [8][E] scores
    int*   EI  = (int*)(S + (size_t)E * 8);// int32 indices, 2*E
    short* WB  = (short*)(EI + 2 * E);     // 4 x 16384 bf16 weights
    float* mpart = (float*)(WB + 65536);   // [8][EB]
    float* zpart = mpart + (size_t)8 * EB; // [8][EB]
    float* MZ    = zpart + (size_t)8 * EB; // 16: M[8], Z[8]
    int*   flag  = (int*)(MZ + 16);

    // CSR structures alias the Qb buffer (dead after edge_score_stats).
    int* deg      = (int*)Qb;
    int* rowstart = deg + N;
    int* cursor   = rowstart + N + 1;
    int* bsum     = cursor + N;
    int* elist    = bsum + 512;

    // Normalize edge_index to int32; convert weights to bf16.
    detect_i64_kernel<<<1, 64, 0, stream>>>((const int*)eraw, flag);
    conv_idx_kernel<<<(2 * E + TPB - 1) / TPB, TPB, 0, stream>>>(eraw, 2 * E, flag, EI);
    wconv_kernel<<<256, TPB, 0, stream>>>(Wq, Wk, Wv, Wo, WB);

    // Q/K/V projections -> head-major bf16.
    const int gb = (N + 127) / 128;
    gemm_w_kernel<true><<<gb, TPB, 0, stream>>>(feat, N, N, WB,             bq, Qb);
    gemm_w_kernel<true><<<gb, TPB, 0, stream>>>(feat, N, N, WB + 16384,     bk, Kb);
    gemm_w_kernel<true><<<gb, TPB, 0, stream>>>(feat, N, N, WB + 2 * 16384, bv, Vb);

    // Edge scores + online softmax partials (per-head, L2-resident Q/K slices).
    dim3 egrid(EB, 8);
    edge_score_stats_kernel<<<egrid, TPB, 0, stream>>>(Qb, Kb, EI, E, N, S, mpart, zpart);

    // CSR build (Qb region now reusable).
    const int ebE = (E + TPB - 1) / TPB;
    const int nbS = (N + TPB - 1) / TPB;
    hipMemsetAsync(deg, 0, (size_t)N * sizeof(int), stream);
    hist_kernel<<<ebE, TPB, 0, stream>>>(EI, E, deg);
    scan1_kernel<<<nbS, TPB, 0, stream>>>(deg, N, rowstart, bsum);
    scan2_kernel<<<1, 512, 0, stream>>>(bsum, nbS);
    scan3_kernel<<<nbS, TPB, 0, stream>>>(rowstart, N, E, bsum);
    hipMemcpyAsync(cursor, rowstart, (size_t)N * sizeof(int),
                   hipMemcpyDeviceToDevice, stream);
    fill_kernel<<<ebE, TPB, 0, stream>>>(EI, E, cursor, elist);

    // Combine softmax partials.
    stats_reduce_kernel<<<8, TPB, 0, stream>>>(mpart, zpart, EB, MZ);

    // Per-head gather segment-sum with fused exp/normalize.
    dim3 ggrid((N + TPB - 1) / TPB, 8);
    gather_kernel<<<ggrid, TPB, 0, stream>>>(S, Vb, EI + E, rowstart, elist, MZ, N, E, ACC);

    // Output projection (fp32 row-major out).
    gemm_w_kernel<false><<<gb, TPB, 0, stream>>>(ACC, N, N, WB + 3 * 16384, bo, (float*)d_out);
}

// Round 6
// 312.747 us; speedup vs baseline: 1.6325x; 1.6325x over previous
//
#include <hip/hip_runtime.h>

// HyperbolicAttention: N=100000 nodes, C=128, H=8 heads, D=16, E=640000 edges.
// Round 6: row-major bf16 Q/K/V/ACC (lane-level row sharing in gather/scores),
//          swapped-operand LDS MFMA GEMM with vectorized stores, softmax stats
//          fused into edge scores, bf16 ACC into the out-projection.

#define TPB 256

typedef __attribute__((ext_vector_type(8))) short short8;
typedef __attribute__((ext_vector_type(4))) short short4v;
typedef __attribute__((ext_vector_type(4))) float f32x4;

// fp32 -> bf16 round-to-nearest-even
__device__ __forceinline__ short f2bf(float f) {
    unsigned u = __float_as_uint(f);
    u += 0x7fffu + ((u >> 16) & 1u);
    return (short)(u >> 16);
}
// bf16 -> fp32
__device__ __forceinline__ float bf2f(short s) {
    return __uint_as_float(((unsigned)(unsigned short)s) << 16);
}

// ---------------------------------------------------------------------------
// Convert the four 128x128 fp32 weight matrices to bf16 (row-major, packed).
// ---------------------------------------------------------------------------
__global__ void wconv_kernel(const float* __restrict__ W0, const float* __restrict__ W1,
                             const float* __restrict__ W2, const float* __restrict__ W3,
                             short* __restrict__ out)
{
    int i = blockIdx.x * TPB + threadIdx.x;   // 0..65535
    if (i >= 65536) return;
    const float* W = (i < 16384) ? W0 : (i < 32768) ? W1 : (i < 49152) ? W2 : W3;
    out[i] = f2bf(W[i & 16383]);
}

// ---------------------------------------------------------------------------
// Y = X @ W^T + b. W bf16 [128][128] staged in LDS frag-major.
// Swapped-operand MFMA: acc = mfma(Wfrag, Xfrag, acc) -> lane holds x-row=l15,
// 4 consecutive output cols n*16+lh*4+j -> vectorized 8B/16B stores.
// Block = 4 waves x 32 rows = 128 rows.
// IN_BF16:  X is bf16 [nrows][128] (direct short8 A-frag loads).
// OUT_BF16: Y is bf16 [nrows][128]; else fp32 [nrows][128].
// ---------------------------------------------------------------------------
template<bool IN_BF16, bool OUT_BF16>
__global__ __launch_bounds__(256) void gemm_w_kernel(
    const void* __restrict__ Xv, int nrows,
    const short* __restrict__ Wb, const float* __restrict__ bias,
    void* __restrict__ Yv)
{
    __shared__ short lw[16384];   // 32 KiB W, frag-major
    const int tid = threadIdx.x;

    #pragma unroll
    for (int r = 0; r < 8; ++r) {
        int c = r * 256 + tid;              // chunk id 0..2047
        int fragid = c >> 6, ln = c & 63;
        int n = fragid >> 2, kc = fragid & 3;
        int row = n * 16 + (ln & 15);
        int col = kc * 32 + (ln >> 4) * 8;
        *(short8*)&lw[c * 8] = *(const short8*)&Wb[row * 128 + col];
    }
    __syncthreads();

    const int wid = tid >> 6;
    const int lane = tid & 63;
    const int l15 = lane & 15;
    const int lh  = lane >> 4;
    const int rowbase = blockIdx.x * 128 + wid * 32;

    f32x4 acc[8][2];
    #pragma unroll
    for (int n = 0; n < 8; ++n) { acc[n][0] = (f32x4)0.f; acc[n][1] = (f32x4)0.f; }

    const int r0 = rowbase + l15, r1 = r0 + 16;
    const bool v0 = r0 < nrows, v1 = r1 < nrows;

    #pragma unroll
    for (int kc = 0; kc < 4; ++kc) {
        short8 xf[2];
        if (IN_BF16) {
            const short* Xb = (const short*)Xv;
            xf[0] = v0 ? *(const short8*)&Xb[(size_t)r0 * 128 + kc*32 + lh*8]
                       : (short8)(short)0;
            xf[1] = v1 ? *(const short8*)&Xb[(size_t)r1 * 128 + kc*32 + lh*8]
                       : (short8)(short)0;
        } else {
            const float* Xf = (const float*)Xv;
            xf[0] = (short8)(short)0; xf[1] = (short8)(short)0;
            if (v0) {
                const float4* p = (const float4*)(Xf + (size_t)r0 * 128);
                float4 a = p[kc*8 + lh*2], b = p[kc*8 + lh*2 + 1];
                xf[0][0]=f2bf(a.x); xf[0][1]=f2bf(a.y); xf[0][2]=f2bf(a.z); xf[0][3]=f2bf(a.w);
                xf[0][4]=f2bf(b.x); xf[0][5]=f2bf(b.y); xf[0][6]=f2bf(b.z); xf[0][7]=f2bf(b.w);
            }
            if (v1) {
                const float4* p = (const float4*)(Xf + (size_t)r1 * 128);
                float4 a = p[kc*8 + lh*2], b = p[kc*8 + lh*2 + 1];
                xf[1][0]=f2bf(a.x); xf[1][1]=f2bf(a.y); xf[1][2]=f2bf(a.z); xf[1][3]=f2bf(a.w);
                xf[1][4]=f2bf(b.x); xf[1][5]=f2bf(b.y); xf[1][6]=f2bf(b.z); xf[1][7]=f2bf(b.w);
            }
        }
        short8 wf[8];
        #pragma unroll
        for (int n = 0; n < 8; ++n)
            wf[n] = *(const short8*)&lw[((n*4 + kc)*64 + lane) * 8];
        #pragma unroll
        for (int n = 0; n < 8; ++n) {
            acc[n][0] = __builtin_amdgcn_mfma_f32_16x16x32_bf16(wf[n], xf[0], acc[n][0], 0, 0, 0);
            acc[n][1] = __builtin_amdgcn_mfma_f32_16x16x32_bf16(wf[n], xf[1], acc[n][1], 0, 0, 0);
        }
    }

    #pragma unroll
    for (int g = 0; g < 2; ++g) {
        int row = rowbase + g*16 + l15;
        if (row >= nrows) continue;
        #pragma unroll
        for (int n = 0; n < 8; ++n) {
            float4 b4 = *(const float4*)&bias[n*16 + lh*4];
            float y0 = acc[n][g][0] + b4.x;
            float y1 = acc[n][g][1] + b4.y;
            float y2 = acc[n][g][2] + b4.z;
            float y3 = acc[n][g][3] + b4.w;
            if (OUT_BF16) {
                short4v s; s[0]=f2bf(y0); s[1]=f2bf(y1); s[2]=f2bf(y2); s[3]=f2bf(y3);
                *(short4v*)&((short*)Yv)[(size_t)row * 128 + n*16 + lh*4] = s;
            } else {
                *(float4*)&((float*)Yv)[(size_t)row * 128 + n*16 + lh*4] =
                    make_float4(y0, y1, y2, y3);
            }
        }
    }
}

// ---------------------------------------------------------------------------
// edge_index may arrive as int64 (reference) or int32. Detect on device.
// ---------------------------------------------------------------------------
__global__ void detect_i64_kernel(const int* __restrict__ raw, int* __restrict__ flag)
{
    if (blockIdx.x == 0 && threadIdx.x == 0) {
        int odd_nonzero = 0;
        for (int i = 0; i < 128; ++i)
            if (raw[2 * i + 1] != 0) odd_nonzero = 1;
        *flag = odd_nonzero ? 0 : 1;  // 1 => int64 layout
    }
}

__global__ void conv_idx_kernel(const void* __restrict__ raw, int n,
                                const int* __restrict__ flag, int* __restrict__ out)
{
    int i = blockIdx.x * TPB + threadIdx.x;
    if (i >= n) return;
    if (*flag) out[i] = (int)((const long long*)raw)[i];
    else       out[i] = ((const int*)raw)[i];
}

// ---------------------------------------------------------------------------
// Per-edge per-head scores + fused online softmax partials.
// thread = (e,h) with h = idx&7 -> 8 lanes of a node share the 256B Q/K rows.
// Grid-stride (stride multiple of 8 keeps head class fixed per thread).
// ---------------------------------------------------------------------------
__global__ __launch_bounds__(256) void edge_score_stats_kernel(
    const short* __restrict__ Qb, const short* __restrict__ Kb,
    const int* __restrict__ ei, int E, int EH,
    float* __restrict__ S, float* __restrict__ mpart, float* __restrict__ zpart)
{
    int t = threadIdx.x;
    int stride = gridDim.x * TPB;
    float m = -3.0e38f, z = 0.f;
    for (int idx = blockIdx.x * TPB + t; idx < EH; idx += stride) {
        int e = idx >> 3, h = idx & 7;
        int r = ei[e], c = ei[E + e];
        const short8* q8 = (const short8*)(Qb + (size_t)r * 128 + h * 16);
        const short8* k8 = (const short8*)(Kb + (size_t)c * 128 + h * 16);
        short8 q0 = q8[0], q1 = q8[1], k0 = k8[0], k1 = k8[1];
        float dot = 0.f;
        #pragma unroll
        for (int i = 0; i < 8; ++i) {
            dot += bf2f(q0[i]) * bf2f(k0[i]);
            dot += bf2f(q1[i]) * bf2f(k1[i]);
        }
        float s = dot * 0.25f;  // 1/sqrt(16)
        S[idx] = s;
        float M = fmaxf(m, s);
        z = z * __expf(m - M) + __expf(s - M);
        m = M;
    }
    __shared__ float sm[TPB], sz[TPB];
    sm[t] = m; sz[t] = z;
    __syncthreads();
    for (int off = 128; off >= 8; off >>= 1) {
        if (t < off) {
            float m2 = sm[t + off], z2 = sz[t + off];
            float M = fmaxf(sm[t], m2);
            sz[t] = sz[t] * __expf(sm[t] - M) + z2 * __expf(m2 - M);
            sm[t] = M;
        }
        __syncthreads();
    }
    if (t < 8) {
        mpart[blockIdx.x * 8 + t] = sm[t];
        zpart[blockIdx.x * 8 + t] = sz[t];
    }
}

// One block: combine nb per-block partials -> MZ[h] (max), MZ[8+h] (Z).
__global__ void stats_reduce_kernel(const float* __restrict__ mpart,
                                    const float* __restrict__ zpart,
                                    int nb, float* __restrict__ MZ)
{
    int t = threadIdx.x;
    int h = t & 7, chunk = t >> 3;   // 32 chunks
    float m = -3.0e38f, z = 0.f;
    for (int i = chunk; i < nb; i += 32) {
        float m2 = mpart[i * 8 + h], z2 = zpart[i * 8 + h];
        float M = fmaxf(m, m2);
        z = z * __expf(m - M) + z2 * __expf(m2 - M);
        m = M;
    }
    __shared__ float sm[TPB], sz[TPB];
    sm[t] = m; sz[t] = z;
    __syncthreads();
    for (int off = 128; off >= 8; off >>= 1) {
        if (t < off) {
            float m2 = sm[t + off], z2 = sz[t + off];
            float M = fmaxf(sm[t], m2);
            sz[t] = sz[t] * __expf(sm[t] - M) + z2 * __expf(m2 - M);
            sm[t] = M;
        }
        __syncthreads();
    }
    if (t < 8) { MZ[t] = sm[t]; MZ[8 + t] = sz[t]; }
}

// ---------------------------------------------------------------------------
// CSR build: histogram by destination row, exclusive scan, binned fill.
// ---------------------------------------------------------------------------
__global__ void hist_kernel(const int* __restrict__ rows, int E, int* __restrict__ deg)
{
    int e = blockIdx.x * TPB + threadIdx.x;
    if (e < E) atomicAdd(&deg[rows[e]], 1);
}

__global__ void scan1_kernel(const int* __restrict__ deg, int n,
                             int* __restrict__ rowstart, int* __restrict__ bsum)
{
    __shared__ int sm[TPB];
    int t = threadIdx.x;
    int gid = blockIdx.x * TPB + t;
    int v = (gid < n) ? deg[gid] : 0;
    sm[t] = v;
    __syncthreads();
    for (int off = 1; off < TPB; off <<= 1) {
        int x = (t >= off) ? sm[t - off] : 0;
        __syncthreads();
        sm[t] += x;
        __syncthreads();
    }
    if (gid < n) rowstart[gid] = sm[t] - v;
    if (t == TPB - 1) bsum[blockIdx.x] = sm[t];
}

__global__ void scan2_kernel(int* __restrict__ bsum, int nb)
{
    __shared__ int sm[512];
    int t = threadIdx.x;
    int v = (t < nb) ? bsum[t] : 0;
    sm[t] = v;
    __syncthreads();
    for (int off = 1; off < 512; off <<= 1) {
        int x = (t >= off) ? sm[t - off] : 0;
        __syncthreads();
        sm[t] += x;
        __syncthreads();
    }
    if (t < nb) bsum[t] = sm[t] - v;
}

__global__ void scan3_kernel(int* __restrict__ rowstart, int n, int E,
                             const int* __restrict__ bsum)
{
    int gid = blockIdx.x * TPB + threadIdx.x;
    if (gid < n) rowstart[gid] += bsum[blockIdx.x];
    if (gid == 0) rowstart[n] = E;
}

__global__ void fill_kernel(const int* __restrict__ rows, int E,
                            int* __restrict__ cursor, int* __restrict__ elist)
{
    int e = blockIdx.x * TPB + threadIdx.x;
    if (e >= E) return;
    int pos = atomicAdd(&cursor[rows[e]], 1);
    elist[pos] = e;
}

// ---------------------------------------------------------------------------
// Gather segment-sum, fused exp/normalize: thread = (node, head), h = idx&7
// -> 8 lanes share the 256B V row and the 32B S chunk per edge.
// Writes bf16 ACC row-major.
// ---------------------------------------------------------------------------
__global__ __launch_bounds__(256) void gather_kernel(
    const float* __restrict__ S, const short* __restrict__ Vb,
    const int* __restrict__ cols,
    const int* __restrict__ rowstart, const int* __restrict__ elist,
    const float* __restrict__ MZ, int N,
    short* __restrict__ outb)
{
    int idx = blockIdx.x * TPB + threadIdx.x;
    if (idx >= N * 8) return;
    int node = idx >> 3, h = idx & 7;
    float M = MZ[h];
    float invZ = 1.0f / MZ[8 + h];
    int p0 = rowstart[node], p1 = rowstart[node + 1];

    float a[16];
    #pragma unroll
    for (int i = 0; i < 16; ++i) a[i] = 0.f;

    for (int p = p0; p < p1; ++p) {
        int e = elist[p];
        int c = cols[e];
        float w = __expf(S[e * 8 + h] - M) * invZ;
        const short8* v8 = (const short8*)(Vb + (size_t)c * 128 + h * 16);
        short8 v0 = v8[0], v1 = v8[1];
        #pragma unroll
        for (int i = 0; i < 8; ++i) {
            a[i]     += w * bf2f(v0[i]);
            a[8 + i] += w * bf2f(v1[i]);
        }
    }
    short8 o0, o1;
    #pragma unroll
    for (int i = 0; i < 8; ++i) { o0[i] = f2bf(a[i]); o1[i] = f2bf(a[8 + i]); }
    short8* ob = (short8*)(outb + (size_t)node * 128 + h * 16);
    ob[0] = o0; ob[1] = o1;
}

// ---------------------------------------------------------------------------
extern "C" void kernel_launch(void* const* d_in, const int* in_sizes, int n_in,
                              void* d_out, int out_size, void* d_ws, size_t ws_size,
                              hipStream_t stream)
{
    const float* feat = (const float*)d_in[0];
    const void*  eraw = d_in[1];
    const float* Wq = (const float*)d_in[2];
    const float* bq = (const float*)d_in[3];
    const float* Wk = (const float*)d_in[4];
    const float* bk = (const float*)d_in[5];
    const float* Wv = (const float*)d_in[6];
    const float* bv = (const float*)d_in[7];
    const float* Wo = (const float*)d_in[8];
    const float* bo = (const float*)d_in[9];

    const int N = in_sizes[0] / 128;
    const int E = in_sizes[1] / 2;
    const size_t NC = (size_t)N * 128;
    const int EH = E * 8;
    const int EG = 2500;   // edge-stats grid (grid-stride)

    // Workspace layout
    short* Qb   = (short*)d_ws;            // [N][128] bf16
    short* Kb   = Qb + NC;                 // [N][128] bf16
    short* Vb   = Kb + NC;                 // [N][128] bf16
    short* ACCb = Vb + NC;                 // [N][128] bf16
    float* S    = (float*)(ACCb + NC);     // [E*8] scores
    int*   EI   = (int*)(S + EH);          // int32 indices, 2*E
    short* WB   = (short*)(EI + 2 * E);    // 4 x 16384 bf16 weights
    float* mpart = (float*)(WB + 65536);   // [EG][8]
    float* zpart = mpart + (size_t)EG * 8; // [EG][8]
    float* MZ    = zpart + (size_t)EG * 8; // 16: M[8], Z[8]
    int*   flag  = (int*)(MZ + 16);

    // CSR structures alias the Qb buffer (dead after edge_score_stats).
    int* deg      = (int*)Qb;
    int* rowstart = deg + N;
    int* cursor   = rowstart + N + 1;
    int* bsum     = cursor + N;
    int* elist    = bsum + 512;

    // Normalize edge_index to int32; convert weights to bf16.
    detect_i64_kernel<<<1, 64, 0, stream>>>((const int*)eraw, flag);
    conv_idx_kernel<<<(2 * E + TPB - 1) / TPB, TPB, 0, stream>>>(eraw, 2 * E, flag, EI);
    wconv_kernel<<<256, TPB, 0, stream>>>(Wq, Wk, Wv, Wo, WB);

    // Q/K/V projections -> row-major bf16.
    const int gb = (N + 127) / 128;
    gemm_w_kernel<false, true><<<gb, TPB, 0, stream>>>(feat, N, WB,             bq, Qb);
    gemm_w_kernel<false, true><<<gb, TPB, 0, stream>>>(feat, N, WB + 16384,     bk, Kb);
    gemm_w_kernel<false, true><<<gb, TPB, 0, stream>>>(feat, N, WB + 2 * 16384, bv, Vb);

    // Edge scores + fused online softmax partials.
    edge_score_stats_kernel<<<EG, TPB, 0, stream>>>(Qb, Kb, EI, E, EH, S, mpart, zpart);

    // CSR build (Qb region now reusable).
    const int ebE = (E + TPB - 1) / TPB;
    const int nbS = (N + TPB - 1) / TPB;
    hipMemsetAsync(deg, 0, (size_t)N * sizeof(int), stream);
    hist_kernel<<<ebE, TPB, 0, stream>>>(EI, E, deg);
    scan1_kernel<<<nbS, TPB, 0, stream>>>(deg, N, rowstart, bsum);
    scan2_kernel<<<1, 512, 0, stream>>>(bsum, nbS);
    scan3_kernel<<<nbS, TPB, 0, stream>>>(rowstart, N, E, bsum);
    hipMemcpyAsync(cursor, rowstart, (size_t)N * sizeof(int),
                   hipMemcpyDeviceToDevice, stream);
    fill_kernel<<<ebE, TPB, 0, stream>>>(EI, E, cursor, elist);

    // Combine softmax partials.
    stats_reduce_kernel<<<1, TPB, 0, stream>>>(mpart, zpart, EG, MZ);

    // Gather segment-sum with fused exp/normalize -> bf16 ACC.
    const int gbN = (N * 8 + TPB - 1) / TPB;
    gather_kernel<<<gbN, TPB, 0, stream>>>(S, Vb, EI + E, rowstart, elist, MZ, N, ACCb);

    // Output projection (bf16 in, fp32 out).
    gemm_w_kernel<true, false><<<gb, TPB, 0, stream>>>(ACCb, N, WB + 3 * 16384, bo, (float*)d_out);
}

// Round 7
// 268.204 us; speedup vs baseline: 1.9037x; 1.1661x over previous
//
#include <hip/hip_runtime.h>

// HyperbolicAttention: N=100000 nodes, C=128, H=8 heads, D=16, E=640000 edges.
// Round 7: CSR-FIRST pipeline. conv+hist fused, CSR (rowstart, ecol) built
//          before scores; scores run in CSR order (Q in regs, S sequential);
//          gather reads S sequentially; QKV GEMM single gridDim.y=3 launch.

#define TPB 256

typedef __attribute__((ext_vector_type(8))) short short8;
typedef __attribute__((ext_vector_type(4))) short short4v;
typedef __attribute__((ext_vector_type(4))) float f32x4;

// fp32 -> bf16 round-to-nearest-even
__device__ __forceinline__ short f2bf(float f) {
    unsigned u = __float_as_uint(f);
    u += 0x7fffu + ((u >> 16) & 1u);
    return (short)(u >> 16);
}
// bf16 -> fp32
__device__ __forceinline__ float bf2f(short s) {
    return __uint_as_float(((unsigned)(unsigned short)s) << 16);
}

// ---------------------------------------------------------------------------
// Convert the four 128x128 fp32 weight matrices to bf16 (row-major, packed).
// ---------------------------------------------------------------------------
__global__ void wconv_kernel(const float* __restrict__ W0, const float* __restrict__ W1,
                             const float* __restrict__ W2, const float* __restrict__ W3,
                             short* __restrict__ out)
{
    int i = blockIdx.x * TPB + threadIdx.x;   // 0..65535
    if (i >= 65536) return;
    const float* W = (i < 16384) ? W0 : (i < 32768) ? W1 : (i < 49152) ? W2 : W3;
    out[i] = f2bf(W[i & 16383]);
}

// ---------------------------------------------------------------------------
// Shared GEMM body: Y = X @ W^T + b. W bf16 [128][128] staged in LDS
// frag-major. Swapped-operand MFMA -> lane holds x-row=l15, 4 consecutive
// output cols -> vectorized stores. Block = 4 waves x 32 rows = 128 rows.
// ---------------------------------------------------------------------------
template<bool IN_BF16, bool OUT_BF16>
__device__ __forceinline__ void gemm_body(
    const void* __restrict__ Xv, int nrows,
    const short* __restrict__ Wb, const float* __restrict__ bias,
    void* __restrict__ Yv)
{
    __shared__ short lw[16384];   // 32 KiB W, frag-major
    const int tid = threadIdx.x;

    #pragma unroll
    for (int r = 0; r < 8; ++r) {
        int c = r * 256 + tid;              // chunk id 0..2047
        int fragid = c >> 6, ln = c & 63;
        int n = fragid >> 2, kc = fragid & 3;
        int row = n * 16 + (ln & 15);
        int col = kc * 32 + (ln >> 4) * 8;
        *(short8*)&lw[c * 8] = *(const short8*)&Wb[row * 128 + col];
    }
    __syncthreads();

    const int wid = tid >> 6;
    const int lane = tid & 63;
    const int l15 = lane & 15;
    const int lh  = lane >> 4;
    const int rowbase = blockIdx.x * 128 + wid * 32;

    f32x4 acc[8][2];
    #pragma unroll
    for (int n = 0; n < 8; ++n) { acc[n][0] = (f32x4)0.f; acc[n][1] = (f32x4)0.f; }

    const int r0 = rowbase + l15, r1 = r0 + 16;
    const bool v0 = r0 < nrows, v1 = r1 < nrows;

    #pragma unroll
    for (int kc = 0; kc < 4; ++kc) {
        short8 xf[2];
        if (IN_BF16) {
            const short* Xb = (const short*)Xv;
            xf[0] = v0 ? *(const short8*)&Xb[(size_t)r0 * 128 + kc*32 + lh*8]
                       : (short8)(short)0;
            xf[1] = v1 ? *(const short8*)&Xb[(size_t)r1 * 128 + kc*32 + lh*8]
                       : (short8)(short)0;
        } else {
            const float* Xf = (const float*)Xv;
            xf[0] = (short8)(short)0; xf[1] = (short8)(short)0;
            if (v0) {
                const float4* p = (const float4*)(Xf + (size_t)r0 * 128);
                float4 a = p[kc*8 + lh*2], b = p[kc*8 + lh*2 + 1];
                xf[0][0]=f2bf(a.x); xf[0][1]=f2bf(a.y); xf[0][2]=f2bf(a.z); xf[0][3]=f2bf(a.w);
                xf[0][4]=f2bf(b.x); xf[0][5]=f2bf(b.y); xf[0][6]=f2bf(b.z); xf[0][7]=f2bf(b.w);
            }
            if (v1) {
                const float4* p = (const float4*)(Xf + (size_t)r1 * 128);
                float4 a = p[kc*8 + lh*2], b = p[kc*8 + lh*2 + 1];
                xf[1][0]=f2bf(a.x); xf[1][1]=f2bf(a.y); xf[1][2]=f2bf(a.z); xf[1][3]=f2bf(a.w);
                xf[1][4]=f2bf(b.x); xf[1][5]=f2bf(b.y); xf[1][6]=f2bf(b.z); xf[1][7]=f2bf(b.w);
            }
        }
        short8 wf[8];
        #pragma unroll
        for (int n = 0; n < 8; ++n)
            wf[n] = *(const short8*)&lw[((n*4 + kc)*64 + lane) * 8];
        #pragma unroll
        for (int n = 0; n < 8; ++n) {
            acc[n][0] = __builtin_amdgcn_mfma_f32_16x16x32_bf16(wf[n], xf[0], acc[n][0], 0, 0, 0);
            acc[n][1] = __builtin_amdgcn_mfma_f32_16x16x32_bf16(wf[n], xf[1], acc[n][1], 0, 0, 0);
        }
    }

    #pragma unroll
    for (int g = 0; g < 2; ++g) {
        int row = rowbase + g*16 + l15;
        if (row >= nrows) continue;
        #pragma unroll
        for (int n = 0; n < 8; ++n) {
            float4 b4 = *(const float4*)&bias[n*16 + lh*4];
            float y0 = acc[n][g][0] + b4.x;
            float y1 = acc[n][g][1] + b4.y;
            float y2 = acc[n][g][2] + b4.z;
            float y3 = acc[n][g][3] + b4.w;
            if (OUT_BF16) {
                short4v s; s[0]=f2bf(y0); s[1]=f2bf(y1); s[2]=f2bf(y2); s[3]=f2bf(y3);
                *(short4v*)&((short*)Yv)[(size_t)row * 128 + n*16 + lh*4] = s;
            } else {
                *(float4*)&((float*)Yv)[(size_t)row * 128 + n*16 + lh*4] =
                    make_float4(y0, y1, y2, y3);
            }
        }
    }
}

// Output projection: bf16 in, fp32 out.
__global__ __launch_bounds__(256) void gemm_out_kernel(
    const short* __restrict__ Xb, int nrows,
    const short* __restrict__ Wb, const float* __restrict__ bias,
    float* __restrict__ Y)
{
    gemm_body<true, false>(Xb, nrows, Wb, bias, Y);
}

// Fused QKV: gridDim.y = 3 selects W/bias/output slice. fp32 in, bf16 out.
__global__ __launch_bounds__(256) void gemm_qkv_kernel(
    const float* __restrict__ X, int nrows,
    const short* __restrict__ WB,
    const float* __restrict__ bq, const float* __restrict__ bk,
    const float* __restrict__ bv,
    short* __restrict__ Yb, size_t slice)
{
    int w = blockIdx.y;
    const float* bias = (w == 0) ? bq : (w == 1) ? bk : bv;
    gemm_body<false, true>(X, nrows, WB + w * 16384, bias, Yb + (size_t)w * slice);
}

// ---------------------------------------------------------------------------
// edge_index may arrive as int64 (reference) or int32. Detect on device.
// ---------------------------------------------------------------------------
__global__ void detect_i64_kernel(const int* __restrict__ raw, int* __restrict__ flag)
{
    if (blockIdx.x == 0 && threadIdx.x == 0) {
        int odd_nonzero = 0;
        for (int i = 0; i < 128; ++i)
            if (raw[2 * i + 1] != 0) odd_nonzero = 1;
        *flag = odd_nonzero ? 0 : 1;  // 1 => int64 layout
    }
}

// Convert to int32; simultaneously histogram destination rows (i < E).
__global__ void conv_hist_kernel(const void* __restrict__ raw, int E,
                                 const int* __restrict__ flag,
                                 int* __restrict__ out, int* __restrict__ deg)
{
    int i = blockIdx.x * TPB + threadIdx.x;
    if (i >= 2 * E) return;
    int v;
    if (*flag) v = (int)((const long long*)raw)[i];
    else       v = ((const int*)raw)[i];
    out[i] = v;
    if (i < E) atomicAdd(&deg[v], 1);
}

// ---------------------------------------------------------------------------
// CSR scan: block-local exclusive scan, block-sum scan, add-back (also
// initializes cursor = rowstart).
// ---------------------------------------------------------------------------
__global__ void scan1_kernel(const int* __restrict__ deg, int n,
                             int* __restrict__ rowstart, int* __restrict__ bsum)
{
    __shared__ int sm[TPB];
    int t = threadIdx.x;
    int gid = blockIdx.x * TPB + t;
    int v = (gid < n) ? deg[gid] : 0;
    sm[t] = v;
    __syncthreads();
    for (int off = 1; off < TPB; off <<= 1) {
        int x = (t >= off) ? sm[t - off] : 0;
        __syncthreads();
        sm[t] += x;
        __syncthreads();
    }
    if (gid < n) rowstart[gid] = sm[t] - v;
    if (t == TPB - 1) bsum[blockIdx.x] = sm[t];
}

__global__ void scan2_kernel(int* __restrict__ bsum, int nb)
{
    __shared__ int sm[512];
    int t = threadIdx.x;
    int v = (t < nb) ? bsum[t] : 0;
    sm[t] = v;
    __syncthreads();
    for (int off = 1; off < 512; off <<= 1) {
        int x = (t >= off) ? sm[t - off] : 0;
        __syncthreads();
        sm[t] += x;
        __syncthreads();
    }
    if (t < nb) bsum[t] = sm[t] - v;
}

__global__ void scan3_kernel(int* __restrict__ rowstart, int* __restrict__ cursor,
                             int n, int E, const int* __restrict__ bsum)
{
    int gid = blockIdx.x * TPB + threadIdx.x;
    if (gid < n) {
        int v = rowstart[gid] + bsum[blockIdx.x];
        rowstart[gid] = v;
        cursor[gid] = v;
    }
    if (gid == 0) rowstart[n] = E;
}

// Bin edges by destination: ecol[p] = col of edge, p in the dest's segment.
__global__ void fill_kernel(const int* __restrict__ ei, int E,
                            int* __restrict__ cursor, int* __restrict__ ecol)
{
    int e = blockIdx.x * TPB + threadIdx.x;
    if (e >= E) return;
    int pos = atomicAdd(&cursor[ei[e]], 1);
    ecol[pos] = ei[E + e];
}

// ---------------------------------------------------------------------------
// CSR-ordered scores + fused online softmax partials.
// thread = (node, h), h = idx&7: Q-row slice kept in registers; K rows
// shared by the node's 8 lanes; S written sequentially at [p*8+h].
// ---------------------------------------------------------------------------
__global__ __launch_bounds__(256) void csr_score_stats_kernel(
    const short* __restrict__ Qb, const short* __restrict__ Kb,
    const int* __restrict__ ecol, const int* __restrict__ rowstart, int N,
    float* __restrict__ S, float* __restrict__ mpart, float* __restrict__ zpart)
{
    int t = threadIdx.x;
    int idx = blockIdx.x * TPB + t;
    float m = -3.0e38f, z = 0.f;
    if (idx < N * 8) {
        int node = idx >> 3, h = idx & 7;
        const short8* q8 = (const short8*)(Qb + (size_t)node * 128 + h * 16);
        short8 q0 = q8[0], q1 = q8[1];
        int p0 = rowstart[node], p1 = rowstart[node + 1];
        for (int p = p0; p < p1; ++p) {
            int c = ecol[p];
            const short8* k8 = (const short8*)(Kb + (size_t)c * 128 + h * 16);
            short8 k0 = k8[0], k1 = k8[1];
            float dot = 0.f;
            #pragma unroll
            for (int i = 0; i < 8; ++i) {
                dot += bf2f(q0[i]) * bf2f(k0[i]);
                dot += bf2f(q1[i]) * bf2f(k1[i]);
            }
            float s = dot * 0.25f;  // 1/sqrt(16)
            S[(size_t)p * 8 + h] = s;
            float M = fmaxf(m, s);
            z = z * __expf(m - M) + __expf(s - M);
            m = M;
        }
    }
    __shared__ float sm[TPB], sz[TPB];
    sm[t] = m; sz[t] = z;
    __syncthreads();
    for (int off = 128; off >= 8; off >>= 1) {
        if (t < off) {
            float m2 = sm[t + off], z2 = sz[t + off];
            float M = fmaxf(sm[t], m2);
            sz[t] = sz[t] * __expf(sm[t] - M) + z2 * __expf(m2 - M);
            sm[t] = M;
        }
        __syncthreads();
    }
    if (t < 8) {
        mpart[blockIdx.x * 8 + t] = sm[t];
        zpart[blockIdx.x * 8 + t] = sz[t];
    }
}

// One block: combine nb per-block partials -> MZ[h] (max), MZ[8+h] (Z).
__global__ void stats_reduce_kernel(const float* __restrict__ mpart,
                                    const float* __restrict__ zpart,
                                    int nb, float* __restrict__ MZ)
{
    int t = threadIdx.x;
    int h = t & 7, chunk = t >> 3;   // 32 chunks
    float m = -3.0e38f, z = 0.f;
    for (int i = chunk; i < nb; i += 32) {
        float m2 = mpart[i * 8 + h], z2 = zpart[i * 8 + h];
        float M = fmaxf(m, m2);
        z = z * __expf(m - M) + z2 * __expf(m2 - M);
        m = M;
    }
    __shared__ float sm[TPB], sz[TPB];
    sm[t] = m; sz[t] = z;
    __syncthreads();
    for (int off = 128; off >= 8; off >>= 1) {
        if (t < off) {
            float m2 = sm[t + off], z2 = sz[t + off];
            float M = fmaxf(sm[t], m2);
            sz[t] = sz[t] * __expf(sm[t] - M) + z2 * __expf(m2 - M);
            sm[t] = M;
        }
        __syncthreads();
    }
    if (t < 8) { MZ[t] = sm[t]; MZ[8 + t] = sz[t]; }
}

// ---------------------------------------------------------------------------
// Gather segment-sum, fused exp/normalize: thread = (node, head).
// S read sequentially; V rows shared by the node's 8 lanes. bf16 out.
// ---------------------------------------------------------------------------
__global__ __launch_bounds__(256) void gather_kernel(
    const float* __restrict__ S, const short* __restrict__ Vb,
    const int* __restrict__ ecol,
    const int* __restrict__ rowstart,
    const float* __restrict__ MZ, int N,
    short* __restrict__ outb)
{
    int idx = blockIdx.x * TPB + threadIdx.x;
    if (idx >= N * 8) return;
    int node = idx >> 3, h = idx & 7;
    float M = MZ[h];
    float invZ = 1.0f / MZ[8 + h];
    int p0 = rowstart[node], p1 = rowstart[node + 1];

    float a[16];
    #pragma unroll
    for (int i = 0; i < 16; ++i) a[i] = 0.f;

    for (int p = p0; p < p1; ++p) {
        int c = ecol[p];
        float w = __expf(S[(size_t)p * 8 + h] - M) * invZ;
        const short8* v8 = (const short8*)(Vb + (size_t)c * 128 + h * 16);
        short8 v0 = v8[0], v1 = v8[1];
        #pragma unroll
        for (int i = 0; i < 8; ++i) {
            a[i]     += w * bf2f(v0[i]);
            a[8 + i] += w * bf2f(v1[i]);
        }
    }
    short8 o0, o1;
    #pragma unroll
    for (int i = 0; i < 8; ++i) { o0[i] = f2bf(a[i]); o1[i] = f2bf(a[8 + i]); }
    short8* ob = (short8*)(outb + (size_t)node * 128 + h * 16);
    ob[0] = o0; ob[1] = o1;
}

// ---------------------------------------------------------------------------
extern "C" void kernel_launch(void* const* d_in, const int* in_sizes, int n_in,
                              void* d_out, int out_size, void* d_ws, size_t ws_size,
                              hipStream_t stream)
{
    const float* feat = (const float*)d_in[0];
    const void*  eraw = d_in[1];
    const float* Wq = (const float*)d_in[2];
    const float* bq = (const float*)d_in[3];
    const float* Wk = (const float*)d_in[4];
    const float* bk = (const float*)d_in[5];
    const float* Wv = (const float*)d_in[6];
    const float* bv = (const float*)d_in[7];
    const float* Wo = (const float*)d_in[8];
    const float* bo = (const float*)d_in[9];

    const int N = in_sizes[0] / 128;
    const int E = in_sizes[1] / 2;
    const size_t NC = (size_t)N * 128;
    const int EH = E * 8;
    const int gbN = (N * 8 + TPB - 1) / TPB;   // node-head grid (scores/gather)

    // Workspace layout
    short* Qb   = (short*)d_ws;            // [N][128] bf16 (Q,K,V contiguous)
    short* Kb   = Qb + NC;
    short* Vb   = Kb + NC;
    short* ACCb = Vb + NC;                 // [N][128] bf16
    float* S    = (float*)(ACCb + NC);     // [E*8] scores, CSR order
    int*   EI   = (int*)(S + EH);          // int32 indices, 2*E
    short* WB   = (short*)(EI + 2 * E);    // 4 x 16384 bf16 weights
    float* mpart = (float*)(WB + 65536);   // [gbN][8]
    float* zpart = mpart + (size_t)gbN * 8;
    float* MZ    = zpart + (size_t)gbN * 8; // 16: M[8], Z[8]
    int*   flag  = (int*)(MZ + 16);
    int* deg      = flag + 16;             // N
    int* rowstart = deg + N;               // N+1
    int* cursor   = rowstart + N + 1;      // N
    int* bsum     = cursor + N;            // 512
    int* ecol     = bsum + 512;            // E (binned cols)

    const int nbS = (N + TPB - 1) / TPB;
    const int ebE = (E + TPB - 1) / TPB;

    // --- CSR build (independent of GEMMs) ---
    hipMemsetAsync(deg, 0, (size_t)N * sizeof(int), stream);
    detect_i64_kernel<<<1, 64, 0, stream>>>((const int*)eraw, flag);
    conv_hist_kernel<<<(2 * E + TPB - 1) / TPB, TPB, 0, stream>>>(eraw, E, flag, EI, deg);
    scan1_kernel<<<nbS, TPB, 0, stream>>>(deg, N, rowstart, bsum);
    scan2_kernel<<<1, 512, 0, stream>>>(bsum, nbS);
    scan3_kernel<<<nbS, TPB, 0, stream>>>(rowstart, cursor, N, E, bsum);
    fill_kernel<<<ebE, TPB, 0, stream>>>(EI, E, cursor, ecol);

    // --- Projections ---
    wconv_kernel<<<256, TPB, 0, stream>>>(Wq, Wk, Wv, Wo, WB);
    const int gb = (N + 127) / 128;
    dim3 qkvgrid(gb, 3);
    gemm_qkv_kernel<<<qkvgrid, TPB, 0, stream>>>(feat, N, WB, bq, bk, bv, Qb, NC);

    // --- Scores + softmax stats (CSR order) ---
    csr_score_stats_kernel<<<gbN, TPB, 0, stream>>>(Qb, Kb, ecol, rowstart, N,
                                                    S, mpart, zpart);
    stats_reduce_kernel<<<1, TPB, 0, stream>>>(mpart, zpart, gbN, MZ);

    // --- Gather segment-sum with fused exp/normalize -> bf16 ACC ---
    gather_kernel<<<gbN, TPB, 0, stream>>>(S, Vb, ecol, rowstart, MZ, N, ACCb);

    // --- Output projection (bf16 in, fp32 out) ---
    gemm_out_kernel<<<gb, TPB, 0, stream>>>(ACCb, N, WB + 3 * 16384, bo, (float*)d_out);
}

// Round 8
// 258.875 us; speedup vs baseline: 1.9723x; 1.0360x over previous
//
#include <hip/hip_runtime.h>

// HyperbolicAttention: N=100000 nodes, C=128, H=8 heads, D=16, E=640000 edges.
// Round 8: GEMM body with all loads issued up-front (24 in flight/wave),
//          XCD-co-located QKV slice mapping (X fetched once per XCD),
//          2-deep software prefetch in CSR scores + gather.

#define TPB 256

typedef __attribute__((ext_vector_type(8))) short short8;
typedef __attribute__((ext_vector_type(4))) short short4v;
typedef __attribute__((ext_vector_type(4))) float f32x4;

// fp32 -> bf16 round-to-nearest-even
__device__ __forceinline__ short f2bf(float f) {
    unsigned u = __float_as_uint(f);
    u += 0x7fffu + ((u >> 16) & 1u);
    return (short)(u >> 16);
}
// bf16 -> fp32
__device__ __forceinline__ float bf2f(short s) {
    return __uint_as_float(((unsigned)(unsigned short)s) << 16);
}

// ---------------------------------------------------------------------------
// Convert the four 128x128 fp32 weight matrices to bf16 (row-major, packed).
// ---------------------------------------------------------------------------
__global__ void wconv_kernel(const float* __restrict__ W0, const float* __restrict__ W1,
                             const float* __restrict__ W2, const float* __restrict__ W3,
                             short* __restrict__ out)
{
    int i = blockIdx.x * TPB + threadIdx.x;   // 0..65535
    if (i >= 65536) return;
    const float* W = (i < 16384) ? W0 : (i < 32768) ? W1 : (i < 49152) ? W2 : W3;
    out[i] = f2bf(W[i & 16383]);
}

// ---------------------------------------------------------------------------
// Shared GEMM body: Y = X @ W^T + b for one 128-row tile (xblk).
// All global loads (8 W-frags + 16 X-float4 / 8 X-short8) issued before any
// wait -> deep MLP per wave. W LDS frag-major; swapped-operand MFMA; lane
// holds x-row=l15 and 4 consecutive output cols -> vectorized stores.
// ---------------------------------------------------------------------------
template<bool IN_BF16, bool OUT_BF16>
__device__ __forceinline__ void gemm_body(
    const void* __restrict__ Xv, int nrows,
    const short* __restrict__ Wb, const float* __restrict__ bias,
    void* __restrict__ Yv, int xblk)
{
    __shared__ short lw[16384];   // 32 KiB W, frag-major
    const int tid = threadIdx.x;

    // --- issue W global loads (8 x 16B per thread) ---
    short8 wreg[8];
    #pragma unroll
    for (int r = 0; r < 8; ++r) {
        int c = r * 256 + tid;              // chunk id 0..2047
        int fragid = c >> 6, ln = c & 63;
        int n = fragid >> 2, kc = fragid & 3;
        wreg[r] = *(const short8*)&Wb[(n*16 + (ln & 15))*128 + kc*32 + (ln >> 4)*8];
    }

    const int wid = tid >> 6;
    const int lane = tid & 63;
    const int l15 = lane & 15;
    const int lh  = lane >> 4;
    const int rowbase = xblk * 128 + wid * 32;
    const int r0 = rowbase + l15, r1 = r0 + 16;
    const bool vv0 = r0 < nrows, vv1 = r1 < nrows;

    // --- issue ALL X loads, then convert ---
    short8 xfr[4][2];   // [kc][row-group]
    if (IN_BF16) {
        const short* Xb = (const short*)Xv;
        #pragma unroll
        for (int kc = 0; kc < 4; ++kc) {
            xfr[kc][0] = vv0 ? *(const short8*)&Xb[(size_t)r0*128 + kc*32 + lh*8]
                             : (short8)(short)0;
            xfr[kc][1] = vv1 ? *(const short8*)&Xb[(size_t)r1*128 + kc*32 + lh*8]
                             : (short8)(short)0;
        }
    } else {
        const float* Xf = (const float*)Xv;
        const float4* P0 = (const float4*)(Xf + (size_t)r0 * 128);
        const float4* P1 = (const float4*)(Xf + (size_t)r1 * 128);
        float4 xa[4][2], xb[4][2];
        #pragma unroll
        for (int kc = 0; kc < 4; ++kc) {
            xa[kc][0] = vv0 ? P0[kc*8 + lh*2]     : make_float4(0.f,0.f,0.f,0.f);
            xb[kc][0] = vv0 ? P0[kc*8 + lh*2 + 1] : make_float4(0.f,0.f,0.f,0.f);
            xa[kc][1] = vv1 ? P1[kc*8 + lh*2]     : make_float4(0.f,0.f,0.f,0.f);
            xb[kc][1] = vv1 ? P1[kc*8 + lh*2 + 1] : make_float4(0.f,0.f,0.f,0.f);
        }
        #pragma unroll
        for (int kc = 0; kc < 4; ++kc)
            #pragma unroll
            for (int g = 0; g < 2; ++g) {
                xfr[kc][g][0] = f2bf(xa[kc][g].x);
                xfr[kc][g][1] = f2bf(xa[kc][g].y);
                xfr[kc][g][2] = f2bf(xa[kc][g].z);
                xfr[kc][g][3] = f2bf(xa[kc][g].w);
                xfr[kc][g][4] = f2bf(xb[kc][g].x);
                xfr[kc][g][5] = f2bf(xb[kc][g].y);
                xfr[kc][g][6] = f2bf(xb[kc][g].z);
                xfr[kc][g][7] = f2bf(xb[kc][g].w);
            }
    }

    // --- W regs -> LDS, barrier ---
    #pragma unroll
    for (int r = 0; r < 8; ++r)
        *(short8*)&lw[(r * 256 + tid) * 8] = wreg[r];
    __syncthreads();

    // --- pure LDS + MFMA loop ---
    f32x4 acc[8][2];
    #pragma unroll
    for (int n = 0; n < 8; ++n) { acc[n][0] = (f32x4)0.f; acc[n][1] = (f32x4)0.f; }

    #pragma unroll
    for (int kc = 0; kc < 4; ++kc) {
        short8 wf[8];
        #pragma unroll
        for (int n = 0; n < 8; ++n)
            wf[n] = *(const short8*)&lw[((n*4 + kc)*64 + lane) * 8];
        #pragma unroll
        for (int n = 0; n < 8; ++n) {
            acc[n][0] = __builtin_amdgcn_mfma_f32_16x16x32_bf16(wf[n], xfr[kc][0], acc[n][0], 0, 0, 0);
            acc[n][1] = __builtin_amdgcn_mfma_f32_16x16x32_bf16(wf[n], xfr[kc][1], acc[n][1], 0, 0, 0);
        }
    }

    // --- epilogue ---
    #pragma unroll
    for (int g = 0; g < 2; ++g) {
        int row = rowbase + g*16 + l15;
        if (row >= nrows) continue;
        #pragma unroll
        for (int n = 0; n < 8; ++n) {
            float4 b4 = *(const float4*)&bias[n*16 + lh*4];
            float y0 = acc[n][g][0] + b4.x;
            float y1 = acc[n][g][1] + b4.y;
            float y2 = acc[n][g][2] + b4.z;
            float y3 = acc[n][g][3] + b4.w;
            if (OUT_BF16) {
                short4v s; s[0]=f2bf(y0); s[1]=f2bf(y1); s[2]=f2bf(y2); s[3]=f2bf(y3);
                *(short4v*)&((short*)Yv)[(size_t)row * 128 + n*16 + lh*4] = s;
            } else {
                *(float4*)&((float*)Yv)[(size_t)row * 128 + n*16 + lh*4] =
                    make_float4(y0, y1, y2, y3);
            }
        }
    }
}

// Output projection: bf16 in, fp32 out.
__global__ __launch_bounds__(256) void gemm_out_kernel(
    const short* __restrict__ Xb, int nrows,
    const short* __restrict__ Wb, const float* __restrict__ bias,
    float* __restrict__ Y)
{
    gemm_body<true, false>(Xb, nrows, Wb, bias, Y, blockIdx.x);
}

// Fused QKV with XCD co-location: the 3 W-slices of X-tile x map to block ids
// b = (x&7) + 8*(3*(x>>3) + w)  ->  all share b%8 (assumed XCD) so the X rows
// are fetched from HBM once per XCD and L2-shared by the other two slices.
__global__ __launch_bounds__(256) void gemm_qkv_kernel(
    const float* __restrict__ X, int nrows, int nxblk,
    const short* __restrict__ WB,
    const float* __restrict__ bq, const float* __restrict__ bk,
    const float* __restrict__ bv,
    short* __restrict__ Yb, size_t slice)
{
    int b = blockIdx.x;
    int k = b & 7, j = b >> 3;
    int jd = j / 3, w = j - 3 * jd;
    int x = k + 8 * jd;
    if (x >= nxblk) return;
    const float* bias = (w == 0) ? bq : (w == 1) ? bk : bv;
    gemm_body<false, true>(X, nrows, WB + w * 16384, bias,
                           Yb + (size_t)w * slice, x);
}

// ---------------------------------------------------------------------------
// edge_index may arrive as int64 (reference) or int32. Detect on device.
// ---------------------------------------------------------------------------
__global__ void detect_i64_kernel(const int* __restrict__ raw, int* __restrict__ flag)
{
    if (blockIdx.x == 0 && threadIdx.x == 0) {
        int odd_nonzero = 0;
        for (int i = 0; i < 128; ++i)
            if (raw[2 * i + 1] != 0) odd_nonzero = 1;
        *flag = odd_nonzero ? 0 : 1;  // 1 => int64 layout
    }
}

// Convert to int32; simultaneously histogram destination rows (i < E).
__global__ void conv_hist_kernel(const void* __restrict__ raw, int E,
                                 const int* __restrict__ flag,
                                 int* __restrict__ out, int* __restrict__ deg)
{
    int i = blockIdx.x * TPB + threadIdx.x;
    if (i >= 2 * E) return;
    int v;
    if (*flag) v = (int)((const long long*)raw)[i];
    else       v = ((const int*)raw)[i];
    out[i] = v;
    if (i < E) atomicAdd(&deg[v], 1);
}

// ---------------------------------------------------------------------------
// CSR scan: block-local exclusive scan, block-sum scan, add-back (also
// initializes cursor = rowstart).
// ---------------------------------------------------------------------------
__global__ void scan1_kernel(const int* __restrict__ deg, int n,
                             int* __restrict__ rowstart, int* __restrict__ bsum)
{
    __shared__ int sm[TPB];
    int t = threadIdx.x;
    int gid = blockIdx.x * TPB + t;
    int v = (gid < n) ? deg[gid] : 0;
    sm[t] = v;
    __syncthreads();
    for (int off = 1; off < TPB; off <<= 1) {
        int x = (t >= off) ? sm[t - off] : 0;
        __syncthreads();
        sm[t] += x;
        __syncthreads();
    }
    if (gid < n) rowstart[gid] = sm[t] - v;
    if (t == TPB - 1) bsum[blockIdx.x] = sm[t];
}

__global__ void scan2_kernel(int* __restrict__ bsum, int nb)
{
    __shared__ int sm[512];
    int t = threadIdx.x;
    int v = (t < nb) ? bsum[t] : 0;
    sm[t] = v;
    __syncthreads();
    for (int off = 1; off < 512; off <<= 1) {
        int x = (t >= off) ? sm[t - off] : 0;
        __syncthreads();
        sm[t] += x;
        __syncthreads();
    }
    if (t < nb) bsum[t] = sm[t] - v;
}

__global__ void scan3_kernel(int* __restrict__ rowstart, int* __restrict__ cursor,
                             int n, int E, const int* __restrict__ bsum)
{
    int gid = blockIdx.x * TPB + threadIdx.x;
    if (gid < n) {
        int v = rowstart[gid] + bsum[blockIdx.x];
        rowstart[gid] = v;
        cursor[gid] = v;
    }
    if (gid == 0) rowstart[n] = E;
}

// Bin edges by destination: ecol[p] = col of edge, p in the dest's segment.
__global__ void fill_kernel(const int* __restrict__ ei, int E,
                            int* __restrict__ cursor, int* __restrict__ ecol)
{
    int e = blockIdx.x * TPB + threadIdx.x;
    if (e >= E) return;
    int pos = atomicAdd(&cursor[ei[e]], 1);
    ecol[pos] = ei[E + e];
}

// ---------------------------------------------------------------------------
// CSR-ordered scores + fused online softmax partials, 2-deep prefetch.
// thread = (node, h): Q slice in regs; K rows shared by the node's 8 lanes;
// S written sequentially at [p*8+h].
// ---------------------------------------------------------------------------
__global__ __launch_bounds__(256) void csr_score_stats_kernel(
    const short* __restrict__ Qb, const short* __restrict__ Kb,
    const int* __restrict__ ecol, const int* __restrict__ rowstart, int N,
    float* __restrict__ S, float* __restrict__ mpart, float* __restrict__ zpart)
{
    int t = threadIdx.x;
    int idx = blockIdx.x * TPB + t;
    float m = -3.0e38f, z = 0.f;
    if (idx < N * 8) {
        int node = idx >> 3, h = idx & 7;
        const short8* q8 = (const short8*)(Qb + (size_t)node * 128 + h * 16);
        short8 q0 = q8[0], q1 = q8[1];
        int p0 = rowstart[node], p1 = rowstart[node + 1];
        if (p0 < p1) {
            const short8* kc = (const short8*)(Kb + (size_t)ecol[p0] * 128 + h * 16);
            short8 k0 = kc[0], k1 = kc[1];
            for (int p = p0; p < p1; ++p) {
                short8 k0n = k0, k1n = k1;
                if (p + 1 < p1) {
                    const short8* kn = (const short8*)(Kb + (size_t)ecol[p+1] * 128 + h * 16);
                    k0n = kn[0]; k1n = kn[1];
                }
                float dot = 0.f;
                #pragma unroll
                for (int i = 0; i < 8; ++i) {
                    dot += bf2f(q0[i]) * bf2f(k0[i]);
                    dot += bf2f(q1[i]) * bf2f(k1[i]);
                }
                float s = dot * 0.25f;  // 1/sqrt(16)
                S[(size_t)p * 8 + h] = s;
                float M = fmaxf(m, s);
                z = z * __expf(m - M) + __expf(s - M);
                m = M;
                k0 = k0n; k1 = k1n;
            }
        }
    }
    __shared__ float sm[TPB], sz[TPB];
    sm[t] = m; sz[t] = z;
    __syncthreads();
    for (int off = 128; off >= 8; off >>= 1) {
        if (t < off) {
            float m2 = sm[t + off], z2 = sz[t + off];
            float M = fmaxf(sm[t], m2);
            sz[t] = sz[t] * __expf(sm[t] - M) + z2 * __expf(m2 - M);
            sm[t] = M;
        }
        __syncthreads();
    }
    if (t < 8) {
        mpart[blockIdx.x * 8 + t] = sm[t];
        zpart[blockIdx.x * 8 + t] = sz[t];
    }
}

// One block: combine nb per-block partials -> MZ[h] (max), MZ[8+h] (Z).
__global__ void stats_reduce_kernel(const float* __restrict__ mpart,
                                    const float* __restrict__ zpart,
                                    int nb, float* __restrict__ MZ)
{
    int t = threadIdx.x;
    int h = t & 7, chunk = t >> 3;   // 32 chunks
    float m = -3.0e38f, z = 0.f;
    for (int i = chunk; i < nb; i += 32) {
        float m2 = mpart[i * 8 + h], z2 = zpart[i * 8 + h];
        float M = fmaxf(m, m2);
        z = z * __expf(m - M) + z2 * __expf(m2 - M);
        m = M;
    }
    __shared__ float sm[TPB], sz[TPB];
    sm[t] = m; sz[t] = z;
    __syncthreads();
    for (int off = 128; off >= 8; off >>= 1) {
        if (t < off) {
            float m2 = sm[t + off], z2 = sz[t + off];
            float M = fmaxf(sm[t], m2);
            sz[t] = sz[t] * __expf(sm[t] - M) + z2 * __expf(m2 - M);
            sm[t] = M;
        }
        __syncthreads();
    }
    if (t < 8) { MZ[t] = sm[t]; MZ[8 + t] = sz[t]; }
}

// ---------------------------------------------------------------------------
// Gather segment-sum, fused exp/normalize, 2-deep prefetch.
// thread = (node, head); S sequential; V rows shared by the node's 8 lanes.
// ---------------------------------------------------------------------------
__global__ __launch_bounds__(256) void gather_kernel(
    const float* __restrict__ S, const short* __restrict__ Vb,
    const int* __restrict__ ecol,
    const int* __restrict__ rowstart,
    const float* __restrict__ MZ, int N,
    short* __restrict__ outb)
{
    int idx = blockIdx.x * TPB + threadIdx.x;
    if (idx >= N * 8) return;
    int node = idx >> 3, h = idx & 7;
    float M = MZ[h];
    float invZ = 1.0f / MZ[8 + h];
    int p0 = rowstart[node], p1 = rowstart[node + 1];

    float a[16];
    #pragma unroll
    for (int i = 0; i < 16; ++i) a[i] = 0.f;

    if (p0 < p1) {
        const short8* vc = (const short8*)(Vb + (size_t)ecol[p0] * 128 + h * 16);
        short8 v0 = vc[0], v1 = vc[1];
        float sc = S[(size_t)p0 * 8 + h];
        for (int p = p0; p < p1; ++p) {
            short8 v0n = v0, v1n = v1;
            float sn = sc;
            if (p + 1 < p1) {
                const short8* vn = (const short8*)(Vb + (size_t)ecol[p+1] * 128 + h * 16);
                v0n = vn[0]; v1n = vn[1];
                sn = S[(size_t)(p+1) * 8 + h];
            }
            float w = __expf(sc - M) * invZ;
            #pragma unroll
            for (int i = 0; i < 8; ++i) {
                a[i]     += w * bf2f(v0[i]);
                a[8 + i] += w * bf2f(v1[i]);
            }
            v0 = v0n; v1 = v1n; sc = sn;
        }
    }
    short8 o0, o1;
    #pragma unroll
    for (int i = 0; i < 8; ++i) { o0[i] = f2bf(a[i]); o1[i] = f2bf(a[8 + i]); }
    short8* ob = (short8*)(outb + (size_t)node * 128 + h * 16);
    ob[0] = o0; ob[1] = o1;
}

// ---------------------------------------------------------------------------
extern "C" void kernel_launch(void* const* d_in, const int* in_sizes, int n_in,
                              void* d_out, int out_size, void* d_ws, size_t ws_size,
                              hipStream_t stream)
{
    const float* feat = (const float*)d_in[0];
    const void*  eraw = d_in[1];
    const float* Wq = (const float*)d_in[2];
    const float* bq = (const float*)d_in[3];
    const float* Wk = (const float*)d_in[4];
    const float* bk = (const float*)d_in[5];
    const float* Wv = (const float*)d_in[6];
    const float* bv = (const float*)d_in[7];
    const float* Wo = (const float*)d_in[8];
    const float* bo = (const float*)d_in[9];

    const int N = in_sizes[0] / 128;
    const int E = in_sizes[1] / 2;
    const size_t NC = (size_t)N * 128;
    const int EH = E * 8;
    const int gbN = (N * 8 + TPB - 1) / TPB;   // node-head grid (scores/gather)

    // Workspace layout
    short* Qb   = (short*)d_ws;            // [N][128] bf16 (Q,K,V contiguous)
    short* Kb   = Qb + NC;
    short* Vb   = Kb + NC;
    short* ACCb = Vb + NC;                 // [N][128] bf16
    float* S    = (float*)(ACCb + NC);     // [E*8] scores, CSR order
    int*   EI   = (int*)(S + EH);          // int32 indices, 2*E
    short* WB   = (short*)(EI + 2 * E);    // 4 x 16384 bf16 weights
    float* mpart = (float*)(WB + 65536);   // [gbN][8]
    float* zpart = mpart + (size_t)gbN * 8;
    float* MZ    = zpart + (size_t)gbN * 8; // 16: M[8], Z[8]
    int*   flag  = (int*)(MZ + 16);
    int* deg      = flag + 16;             // N
    int* rowstart = deg + N;               // N+1
    int* cursor   = rowstart + N + 1;      // N
    int* bsum     = cursor + N;            // 512
    int* ecol     = bsum + 512;            // E (binned cols)

    const int nbS = (N + TPB - 1) / TPB;
    const int ebE = (E + TPB - 1) / TPB;

    // --- CSR build (independent of GEMMs) ---
    hipMemsetAsync(deg, 0, (size_t)N * sizeof(int), stream);
    detect_i64_kernel<<<1, 64, 0, stream>>>((const int*)eraw, flag);
    conv_hist_kernel<<<(2 * E + TPB - 1) / TPB, TPB, 0, stream>>>(eraw, E, flag, EI, deg);
    scan1_kernel<<<nbS, TPB, 0, stream>>>(deg, N, rowstart, bsum);
    scan2_kernel<<<1, 512, 0, stream>>>(bsum, nbS);
    scan3_kernel<<<nbS, TPB, 0, stream>>>(rowstart, cursor, N, E, bsum);
    fill_kernel<<<ebE, TPB, 0, stream>>>(EI, E, cursor, ecol);

    // --- Projections ---
    wconv_kernel<<<256, TPB, 0, stream>>>(Wq, Wk, Wv, Wo, WB);
    const int gb = (N + 127) / 128;                 // X tiles
    const int qkvgrid = 8 * 3 * ((gb + 7) / 8);     // XCD-co-located mapping
    gemm_qkv_kernel<<<qkvgrid, TPB, 0, stream>>>(feat, N, gb, WB, bq, bk, bv, Qb, NC);

    // --- Scores + softmax stats (CSR order) ---
    csr_score_stats_kernel<<<gbN, TPB, 0, stream>>>(Qb, Kb, ecol, rowstart, N,
                                                    S, mpart, zpart);
    stats_reduce_kernel<<<1, TPB, 0, stream>>>(mpart, zpart, gbN, MZ);

    // --- Gather segment-sum with fused exp/normalize -> bf16 ACC ---
    gather_kernel<<<gbN, TPB, 0, stream>>>(S, Vb, ecol, rowstart, MZ, N, ACCb);

    // --- Output projection (bf16 in, fp32 out) ---
    gemm_out_kernel<<<gb, TPB, 0, stream>>>(ACCb, N, WB + 3 * 16384, bo, (float*)d_out);
}